// Round 8
// baseline (992.662 us; speedup 1.0000x reference)
//
#include <hip/hip_runtime.h>
#include <hip/hip_bf16.h>
#include <stdint.h>

#define EDGES 200000
#define INF   128
#define HID   32
#define NHEAD 4
#define OUTF  128
#define MAXK  16

// combined-projection feature count: q(128) g(128) kv(256) b(4) pad(12)
#define NPAD  528

// LDS row stride in u16 for per-edge 128-col tiles (q/g/x)
#define XPAD  136

#define LOG2E 1.44269504088896f
// (1/sqrt(32)) * log2(e)
#define SCALE2 0.2550348612f

typedef unsigned short u16;
typedef __attribute__((ext_vector_type(8))) short bf16x8;   // 8 bf16 = 4 VGPRs
typedef __attribute__((ext_vector_type(4))) float f32x4;

__device__ __forceinline__ u16 f2bf(float f) {   // RNE f32->bf16
  union { float f; uint32_t u; } v; v.f = f;
  uint32_t u = v.u;
  return (u16)((u + 0x7FFFu + ((u >> 16) & 1u)) >> 16);
}
__device__ __forceinline__ float bflo(uint32_t p) {   // low bf16 of packed pair
  union { uint32_t u; float f; } v; v.u = p << 16;
  return v.f;
}
__device__ __forceinline__ float bfhi(uint32_t p) {   // high bf16 of packed pair
  union { uint32_t u; float f; } v; v.u = p & 0xFFFF0000u;
  return v.f;
}

// packed f32x2 -> bf16x2 (RNE), lets compiler emit v_cvt_pk_bf16_f32
__device__ __forceinline__ uint32_t cvtpk_bf16(float lo, float hi) {
  float2 t; t.x = lo; t.y = hi;
  __hip_bfloat162 h = __float22bfloat162_rn(t);
  uint32_t u;
  __builtin_memcpy(&u, &h, 4);
  return u;
}
__device__ __forceinline__ bf16x8 pack8(f32x4 f0, f32x4 f1) {
  union { uint32_t u[4]; bf16x8 v; } r;
  r.u[0] = cvtpk_bf16(f0[0], f0[1]);
  r.u[1] = cvtpk_bf16(f0[2], f0[3]);
  r.u[2] = cvtpk_bf16(f1[0], f1[1]);
  r.u[3] = cvtpk_bf16(f1[2], f1[3]);
  return r.v;
}
__device__ __forceinline__ float sigm(float x) {
  return 1.0f / (1.0f + __expf(-x));
}

// DPP-based add within each 16-lane row (one head). bound_ctrl=1, full masks.
template <int CTRL>
__device__ __forceinline__ float dpp_add(float x) {
  int y = __builtin_amdgcn_update_dpp(0, __builtin_bit_cast(int, x),
                                      CTRL, 0xF, 0xF, true);
  return x + __builtin_bit_cast(float, y);
}
__device__ __forceinline__ float row16_sum(float x) {
  x = dpp_add<0xB1>(x);
  x = dpp_add<0x4E>(x);
  x = dpp_add<0x141>(x);
  x = dpp_add<0x140>(x);
  return x;
}

// one 16(n) x 32(e) output tile: A = W rows (M=n), B = Z/x rows (N=e).
// D per lane: col(e) = lane&15, row(n) = (lane>>4)*4 + r  -> 4 consecutive n.
struct AccPair { f32x4 a, b; };
__device__ __forceinline__ AccPair tile_mm(const u16* __restrict__ W, int row0,
                                           int ml, int blk,
                                           const bf16x8 (&zfr)[2][4], int ldw) {
  bf16x8 wfr[4];
#pragma unroll
  for (int kk = 0; kk < 4; ++kk)
    wfr[kk] = *(const bf16x8*)(W + (size_t)(row0 + ml) * ldw + kk * 32 + blk * 8);
  AccPair r;
  r.a = (f32x4){0.f, 0.f, 0.f, 0.f};
  r.b = (f32x4){0.f, 0.f, 0.f, 0.f};
#pragma unroll
  for (int kk = 0; kk < 4; ++kk) {
    r.a = __builtin_amdgcn_mfma_f32_16x16x32_bf16(wfr[kk], zfr[0][kk], r.a, 0, 0, 0);
    r.b = __builtin_amdgcn_mfma_f32_16x16x32_bf16(wfr[kk], zfr[1][kk], r.b, 0, 0, 0);
  }
  return r;
}

// load + bf16-pack the B-operand fragments (32 edges x K=128) for one wave.
// Z is streamed exactly once per kernel -> NONTEMPORAL loads so the stream
// doesn't evict the (L3-resident) kvb gather working set.
__device__ __forceinline__ void load_zfr(const float* __restrict__ Z, long e0,
                                         int ml, int blk, bf16x8 (&zfr)[2][4]) {
#pragma unroll
  for (int s = 0; s < 2; ++s) {
    const float* zp = Z + (e0 + s * 16 + ml) * INF + blk * 8;
#pragma unroll
    for (int kk = 0; kk < 4; ++kk) {
      f32x4 f0 = __builtin_nontemporal_load((const f32x4*)(zp + kk * 32));
      f32x4 f1 = __builtin_nontemporal_load((const f32x4*)(zp + kk * 32 + 4));
      zfr[s][kk] = pack8(f0, f1);
    }
  }
}

// ---- per-wave LDS staging so every HBM store covers full 128B lines ----
__device__ __forceinline__ void ds_stage_pair(u16* sb, int ml, int blk, int t,
                                              uint2 pa, uint2 pb) {
  const int col2 = (t * 16 + blk * 4) * 2;          // byte col within 128B row
  const int swz = (ml & 7) << 4;
  *(uint2*)((char*)sb + ((ml * 128 + col2) ^ swz)) = pa;           // eA row
  *(uint2*)((char*)sb + (((16 + ml) * 128 + col2) ^ swz)) = pb;    // eB row
}
__device__ __forceinline__ void flush_group(const u16* sb, int lane,
                                            u16* __restrict__ dst, long e0,
                                            int rowu16, int colu16) {
  const int rr = lane >> 3;            // 8 rows per store inst
  const int c8 = (lane & 7) * 8;       // u16 col within the 64-col group
#pragma unroll
  for (int i = 0; i < 4; ++i) {
    const int row = i * 8 + rr;
    bf16x8 v = *(const bf16x8*)((const char*)sb +
                                ((row * 128 + c8 * 2) ^ ((row & 7) << 4)));
    *(bf16x8*)(dst + (e0 + row) * rowu16 + colu16 + c8) = v;
  }
}

// ---------------------------------------------------------------------------
// Kernel 1: repack all projection weights into one bf16 matrix Wc[NPAD][128]
// rows: q 0..127, g 128..255, kv 256..511 INTERLEAVED, b 512..515.
// kv interleave: kvb col c (= Wc row 256+c): h = c>>6, r = c&63, ml = r>>2,
// j = r&3; j in {0,1} -> k dim 2ml+j, j in {2,3} -> v dim 2ml+(j-2).
// This makes each attn lane's k-pair and v-pair ADJACENT (one 8B gather).
// ---------------------------------------------------------------------------
__global__ __launch_bounds__(256) void prep_kernel(
    const float* __restrict__ Wq, const float* __restrict__ Wk,
    const float* __restrict__ Wv, const float* __restrict__ Wb,
    const float* __restrict__ Wg, const float* __restrict__ Wout,
    u16* __restrict__ Wc, u16* __restrict__ Woutb)
{
  int t = blockIdx.x * 256 + threadIdx.x;
  if (t < NPAD * INF) {
    int n = t >> 7, k = t & 127;
    float v = 0.0f;
    if (n < 128)       v = Wq[n * 128 + k];
    else if (n < 256)  v = Wg[(n - 128) * 128 + k];
    else if (n < 512) {
      int c = n - 256, h = c >> 6, r = c & 63, ml = r >> 2, j = r & 3;
      int d = 2 * ml + (j & 1);
      v = (j < 2) ? Wk[(h * 32 + d) * 128 + k] : Wv[(h * 32 + d) * 128 + k];
    } else if (n < 516) v = Wb[(n - 512) * 128 + k];
    Wc[t] = f2bf(v);
  } else if (t < NPAD * INF + OUTF * 128) {
    int u = t - NPAD * INF;
    Woutb[u] = f2bf(Wout[u]);
  }
}

// ---------------------------------------------------------------------------
// Kernel 2: projection GEMM for the GATHERED quantities only:
//   kvb[E x 256] = Z @ Wc[256:512]^T,  bb[E x 4] = (Z @ Wc[512:516]^T)*log2e
// R6/R7 showed proj is latency-bound -> maximize TLP: 32 edges/block
// (6250 blocks), each wave owns ONE 4-tile kv group (4-tile serial chain).
// Z loads duplicate across the 4 waves (L1/L2 hits).
// ---------------------------------------------------------------------------
__global__ __launch_bounds__(256) void proj_kernel(
    const float* __restrict__ Z, const u16* __restrict__ Wc,
    u16* __restrict__ kvb, float* __restrict__ bb)
{
  __shared__ u16 stage[4][2048];   // [wave][32 rows x 64 cols]  (16 KB)

  const int wid = threadIdx.x >> 6, lane = threadIdx.x & 63;
  const int ml = lane & 15, blk = lane >> 4;
  const long e0 = (long)blockIdx.x * 32;

  bf16x8 zfr[2][4];
  load_zfr(Z, e0, ml, blk, zfr);

  // one 4-tile group per wave -> kvb col range [wid*64, wid*64+64)
  {
    u16* sb = stage[wid];
#pragma unroll
    for (int t = 0; t < 4; ++t) {
      AccPair acc = tile_mm(Wc, 256 + (wid * 4 + t) * 16, ml, blk, zfr, INF);
      uint2 pa, pb;
      pa.x = cvtpk_bf16(acc.a[0], acc.a[1]); pa.y = cvtpk_bf16(acc.a[2], acc.a[3]);
      pb.x = cvtpk_bf16(acc.b[0], acc.b[1]); pb.y = cvtpk_bf16(acc.b[2], acc.b[3]);
      ds_stage_pair(sb, ml, blk, t, pa, pb);
    }
    flush_group(sb, lane, kvb, e0, 256, wid * 64);
  }

  // --- b tile: Wc rows 512..515, prescaled by log2(e) for exp2 softmax ---
  if (wid == 3) {
    AccPair acc = tile_mm(Wc, 512, ml, blk, zfr, INF);
    if (blk == 0) {   // rows 512..515 only
      *(f32x4*)(bb + (e0 + ml) * 4) =
          (f32x4){acc.a[0] * LOG2E, acc.a[1] * LOG2E,
                  acc.a[2] * LOG2E, acc.a[3] * LOG2E};
      *(f32x4*)(bb + (e0 + 16 + ml) * 4) =
          (f32x4){acc.b[0] * LOG2E, acc.b[1] * LOG2E,
                  acc.b[2] * LOG2E, acc.b[3] * LOG2E};
    }
  }
}

// ---------------------------------------------------------------------------
// Kernel 3: fused q/g projection + gathered attention + output GEMM.
// Block = 4 waves = 32 edges. xs aliases qs (phase B overwrites q with x
// in-place, wave-exclusive rows). Gather loads one 8B [k-pair|v-pair] per
// lane per neighbor (interleaved kvb layout). Softmax in base-2. Z loads
// and out stores are nontemporal to keep kvb L3-resident.
// ---------------------------------------------------------------------------
__global__ __launch_bounds__(256) void attn_out_kernel(
    const float* __restrict__ Z, const u16* __restrict__ Wc,
    const float* __restrict__ bg,
    const int* __restrict__ klist, const u16* __restrict__ kvb,
    const float* __restrict__ bb, const u16* __restrict__ Woutb,
    const float* __restrict__ bout, float* __restrict__ out)
{
  __shared__ u16 qs[32 * XPAD];    // q in phase A/B, x in phase B/C (aliased)
  __shared__ u16 gs[32 * XPAD];

  const int wid = threadIdx.x >> 6;
  const int lane = threadIdx.x & 63;
  const long e0 = (long)blockIdx.x * 32;
  const int ml = lane & 15, blk = lane >> 4;

  // ---- Phase A: q/g projection for this block's 32 edges ----
  {
    bf16x8 zfr[2][4];
    load_zfr(Z, e0, ml, blk, zfr);

#pragma unroll
    for (int t = 0; t < 2; ++t) {
      const int nt = wid * 2 + t;             // q tile in [0,8)
      AccPair acc = tile_mm(Wc, nt * 16, ml, blk, zfr, INF);
      const int n0 = nt * 16 + blk * 4;
      uint2 pa, pb;
      pa.x = cvtpk_bf16(acc.a[0], acc.a[1]); pa.y = cvtpk_bf16(acc.a[2], acc.a[3]);
      pb.x = cvtpk_bf16(acc.b[0], acc.b[1]); pb.y = cvtpk_bf16(acc.b[2], acc.b[3]);
      *(uint2*)(&qs[ml * XPAD + n0]) = pa;
      *(uint2*)(&qs[(16 + ml) * XPAD + n0]) = pb;
    }
#pragma unroll
    for (int t = 0; t < 2; ++t) {
      const int nt = wid * 2 + t;             // g tile in [0,8)
      AccPair acc = tile_mm(Wc, 128 + nt * 16, ml, blk, zfr, INF);
      const int n0 = nt * 16 + blk * 4;
      f32x4 b4 = *(const f32x4*)(bg + n0);
      uint2 pa, pb;
      pa.x = cvtpk_bf16(sigm(acc.a[0] + b4[0]), sigm(acc.a[1] + b4[1]));
      pa.y = cvtpk_bf16(sigm(acc.a[2] + b4[2]), sigm(acc.a[3] + b4[3]));
      pb.x = cvtpk_bf16(sigm(acc.b[0] + b4[0]), sigm(acc.b[1] + b4[1]));
      pb.y = cvtpk_bf16(sigm(acc.b[2] + b4[2]), sigm(acc.b[3] + b4[3]));
      *(uint2*)(&gs[ml * XPAD + n0]) = pa;
      *(uint2*)(&gs[(16 + ml) * XPAD + n0]) = pb;
    }
  }
  __syncthreads();

  // ---- Phase B: gathered attention, one edge per wave-iteration ----
  const int h = lane >> 4;
  const int kvo = h * 64 + (lane & 15) * 4;   // u16 offset: [k0,k1,v0,v1]

#pragma unroll 1
  for (int it = 0; it < 8; ++it) {
    const int le = wid * 8 + it;
    int e = (int)e0 + le;
    e = __builtin_amdgcn_readfirstlane(e);   // wave-uniform -> SGPR

    const uint32_t q2 = *(const uint32_t*)(&qs[le * XPAD + 2 * lane]);
    const uint32_t g2 = *(const uint32_t*)(&gs[le * XPAD + 2 * lane]);
    const float q0 = bflo(q2), q1 = bfhi(q2);

    float sc[MAXK];
    uint32_t vvm[MAXK];
    const int* kl = klist + (size_t)e * 32;
#pragma unroll
    for (int nb = 0; nb < MAXK; ++nb) {
      const int ii = kl[nb];
      const int jj = kl[16 + nb];
      const bool valid = (ii >= 0);
      const int is = valid ? ii : 0;
      const int js = valid ? jj : 0;
      uint2 kv4 = *(const uint2*)(kvb + (size_t)is * 256 + kvo);  // 8B: k|v
      float p = q0 * bflo(kv4.x) + q1 * bfhi(kv4.x);
      p = row16_sum(p);                                 // head-wide dot
      float bj = bb[(size_t)js * 4 + h];                // prescaled by log2e
      sc[nb]  = valid ? fmaf(SCALE2, p, bj) : 0.0f;     // base-2 score
      vvm[nb] = valid ? kv4.y : 0u;
    }

    float m = sc[0];
#pragma unroll
    for (int nb = 1; nb < MAXK; ++nb) m = fmaxf(m, sc[nb]);
    float s = 0.f, a0 = 0.f, a1 = 0.f;
#pragma unroll
    for (int nb = 0; nb < MAXK; ++nb) {
      float al = exp2f(sc[nb] - m);                     // bare v_exp_f32
      s += al;
      a0 += al * bflo(vvm[nb]);
      a1 += al * bfhi(vvm[nb]);
    }
    float inv = 1.0f / s;
    uint32_t xo = cvtpk_bf16(bflo(g2) * a0 * inv, bfhi(g2) * a1 * inv);
    *(uint32_t*)(&qs[le * XPAD + 2 * lane]) = xo;   // x overwrites q (aliased)
  }

  __syncthreads();

  // ---- Phase C: output GEMM, 32 edges x 128 out, K = 128 ----
  bf16x8 xfr[2][4];
#pragma unroll
  for (int s = 0; s < 2; ++s) {
#pragma unroll
    for (int kk = 0; kk < 4; ++kk)
      xfr[s][kk] = *(const bf16x8*)(&qs[(s * 16 + ml) * XPAD + kk * 32 + blk * 8]);
  }

  const long eA = e0 + ml, eB = e0 + 16 + ml;

#pragma unroll
  for (int t = 0; t < 2; ++t) {
    const int nt = wid * 2 + t;
    AccPair acc = tile_mm(Woutb, nt * 16, ml, blk, xfr, 128);
    const int o0 = nt * 16 + blk * 4;
    f32x4 b4 = *(const f32x4*)(bout + o0);
    f32x4 ra = (f32x4){acc.a[0] + b4[0], acc.a[1] + b4[1],
                       acc.a[2] + b4[2], acc.a[3] + b4[3]};
    f32x4 rb = (f32x4){acc.b[0] + b4[0], acc.b[1] + b4[1],
                       acc.b[2] + b4[2], acc.b[3] + b4[3]};
    __builtin_nontemporal_store(ra, (f32x4*)(out + eA * 128 + o0));
    __builtin_nontemporal_store(rb, (f32x4*)(out + eB * 128 + o0));
  }
}

// ---------------------------------------------------------------------------
extern "C" void kernel_launch(void* const* d_in, const int* in_sizes, int n_in,
                              void* d_out, int out_size, void* d_ws, size_t ws_size,
                              hipStream_t stream) {
  const float* Z     = (const float*)d_in[0];
  const int*   klist = (const int*)  d_in[1];
  const float* Wq    = (const float*)d_in[2];
  const float* Wk    = (const float*)d_in[3];
  const float* Wv    = (const float*)d_in[4];
  const float* Wb    = (const float*)d_in[5];
  const float* Wg    = (const float*)d_in[6];
  const float* bg    = (const float*)d_in[7];
  const float* Wout  = (const float*)d_in[8];
  const float* bout  = (const float*)d_in[9];
  float* out = (float*)d_out;

  char* ws = (char*)d_ws;
  u16*   Wc    = (u16*)(ws);                        //   528*128*2   = 135168
  u16*   Woutb = (u16*)(ws + 135168);               //   128*128*2   =  32768
  u16*   kvb   = (u16*)(ws + 167936);               // E*256*2 = 102.4 MB
  float* bb    = (float*)(ws + 102567936);          // E*4*4   = 3.2 MB

  prep_kernel<<<(NPAD * INF + OUTF * 128 + 255) / 256, 256, 0, stream>>>(
      Wq, Wk, Wv, Wb, Wg, Wout, Wc, Woutb);
  proj_kernel<<<EDGES / 32, 256, 0, stream>>>(
      Z, Wc, kvb, bb);
  attn_out_kernel<<<EDGES / 32, 256, 0, stream>>>(
      Z, Wc, bg, klist, kvb, bb, Woutb, bout, out);
}

// Round 9
// 965.039 us; speedup vs baseline: 1.0286x; 1.0286x over previous
//
#include <hip/hip_runtime.h>
#include <hip/hip_bf16.h>
#include <stdint.h>

#define EDGES 200000
#define INF   128
#define HID   32
#define NHEAD 4
#define OUTF  128
#define MAXK  16

// combined-projection feature count: q(128) g(128) kv(256) b(4) pad(12)
#define NPAD  528

// LDS row stride in u16 for per-edge 128-col tiles (q/g/x)
#define XPAD  136

#define LOG2E 1.44269504088896f
// (1/sqrt(32)) * log2(e)
#define SCALE2 0.2550348612f

typedef unsigned short u16;
typedef __attribute__((ext_vector_type(8))) short bf16x8;   // 8 bf16 = 4 VGPRs
typedef __attribute__((ext_vector_type(4))) float f32x4;

__device__ __forceinline__ u16 f2bf(float f) {   // RNE f32->bf16
  union { float f; uint32_t u; } v; v.f = f;
  uint32_t u = v.u;
  return (u16)((u + 0x7FFFu + ((u >> 16) & 1u)) >> 16);
}
__device__ __forceinline__ float bflo(uint32_t p) {   // low bf16 of packed pair
  union { uint32_t u; float f; } v; v.u = p << 16;
  return v.f;
}
__device__ __forceinline__ float bfhi(uint32_t p) {   // high bf16 of packed pair
  union { uint32_t u; float f; } v; v.u = p & 0xFFFF0000u;
  return v.f;
}

// packed f32x2 -> bf16x2 (RNE), lets compiler emit v_cvt_pk_bf16_f32
__device__ __forceinline__ uint32_t cvtpk_bf16(float lo, float hi) {
  float2 t; t.x = lo; t.y = hi;
  __hip_bfloat162 h = __float22bfloat162_rn(t);
  uint32_t u;
  __builtin_memcpy(&u, &h, 4);
  return u;
}
__device__ __forceinline__ bf16x8 pack8(float4 f0, float4 f1) {
  union { uint32_t u[4]; bf16x8 v; } r;
  r.u[0] = cvtpk_bf16(f0.x, f0.y);
  r.u[1] = cvtpk_bf16(f0.z, f0.w);
  r.u[2] = cvtpk_bf16(f1.x, f1.y);
  r.u[3] = cvtpk_bf16(f1.z, f1.w);
  return r.v;
}
__device__ __forceinline__ float sigm(float x) {
  return 1.0f / (1.0f + __expf(-x));
}

// DPP-based add within each 16-lane row (one head). bound_ctrl=1, full masks.
template <int CTRL>
__device__ __forceinline__ float dpp_add(float x) {
  int y = __builtin_amdgcn_update_dpp(0, __builtin_bit_cast(int, x),
                                      CTRL, 0xF, 0xF, true);
  return x + __builtin_bit_cast(float, y);
}
__device__ __forceinline__ float row16_sum(float x) {
  x = dpp_add<0xB1>(x);
  x = dpp_add<0x4E>(x);
  x = dpp_add<0x141>(x);
  x = dpp_add<0x140>(x);
  return x;
}

// one 16(n) x 32(e) output tile: A = W rows (M=n), B = Z/x rows (N=e).
// D per lane: col(e) = lane&15, row(n) = (lane>>4)*4 + r  -> 4 consecutive n.
struct AccPair { f32x4 a, b; };
__device__ __forceinline__ AccPair tile_mm(const u16* __restrict__ W, int row0,
                                           int ml, int blk,
                                           const bf16x8 (&zfr)[2][4], int ldw) {
  bf16x8 wfr[4];
#pragma unroll
  for (int kk = 0; kk < 4; ++kk)
    wfr[kk] = *(const bf16x8*)(W + (size_t)(row0 + ml) * ldw + kk * 32 + blk * 8);
  AccPair r;
  r.a = (f32x4){0.f, 0.f, 0.f, 0.f};
  r.b = (f32x4){0.f, 0.f, 0.f, 0.f};
#pragma unroll
  for (int kk = 0; kk < 4; ++kk) {
    r.a = __builtin_amdgcn_mfma_f32_16x16x32_bf16(wfr[kk], zfr[0][kk], r.a, 0, 0, 0);
    r.b = __builtin_amdgcn_mfma_f32_16x16x32_bf16(wfr[kk], zfr[1][kk], r.b, 0, 0, 0);
  }
  return r;
}

// load + bf16-pack the B-operand fragments (32 edges x K=128) for one wave.
// Plain cached loads (nontemporal variants regressed 2.7x in R8: nt flag
// bypasses the cache hierarchy on gfx950 and amplifies HBM traffic).
__device__ __forceinline__ void load_zfr(const float* __restrict__ Z, long e0,
                                         int ml, int blk, bf16x8 (&zfr)[2][4]) {
#pragma unroll
  for (int s = 0; s < 2; ++s) {
    const float* zp = Z + (e0 + s * 16 + ml) * INF + blk * 8;
#pragma unroll
    for (int kk = 0; kk < 4; ++kk) {
      float4 f0 = *(const float4*)(zp + kk * 32);
      float4 f1 = *(const float4*)(zp + kk * 32 + 4);
      zfr[s][kk] = pack8(f0, f1);
    }
  }
}

// ---- per-wave LDS staging so every HBM store covers full 128B lines ----
__device__ __forceinline__ void ds_stage_pair(u16* sb, int ml, int blk, int t,
                                              uint2 pa, uint2 pb) {
  const int col2 = (t * 16 + blk * 4) * 2;          // byte col within 128B row
  const int swz = (ml & 7) << 4;
  *(uint2*)((char*)sb + ((ml * 128 + col2) ^ swz)) = pa;           // eA row
  *(uint2*)((char*)sb + (((16 + ml) * 128 + col2) ^ swz)) = pb;    // eB row
}
__device__ __forceinline__ void flush_group(const u16* sb, int lane,
                                            u16* __restrict__ dst, long e0,
                                            int rowu16, int colu16) {
  const int rr = lane >> 3;            // 8 rows per store inst
  const int c8 = (lane & 7) * 8;       // u16 col within the 64-col group
#pragma unroll
  for (int i = 0; i < 4; ++i) {
    const int row = i * 8 + rr;
    bf16x8 v = *(const bf16x8*)((const char*)sb +
                                ((row * 128 + c8 * 2) ^ ((row & 7) << 4)));
    *(bf16x8*)(dst + (e0 + row) * rowu16 + colu16 + c8) = v;
  }
}

// ---------------------------------------------------------------------------
// Kernel 1: repack all projection weights into one bf16 matrix Wc[NPAD][128]
// rows: q 0..127, g 128..255, kv 256..511 INTERLEAVED, b 512..515.
// kv interleave: kvb col c (= Wc row 256+c): h = c>>6, r = c&63, ml = r>>2,
// j = r&3; j in {0,1} -> k dim 2ml+j, j in {2,3} -> v dim 2ml+(j-2).
// This makes each attn lane's k-pair and v-pair ADJACENT (one 8B gather).
// ---------------------------------------------------------------------------
__global__ __launch_bounds__(256) void prep_kernel(
    const float* __restrict__ Wq, const float* __restrict__ Wk,
    const float* __restrict__ Wv, const float* __restrict__ Wb,
    const float* __restrict__ Wg, const float* __restrict__ Wout,
    u16* __restrict__ Wc, u16* __restrict__ Woutb)
{
  int t = blockIdx.x * 256 + threadIdx.x;
  if (t < NPAD * INF) {
    int n = t >> 7, k = t & 127;
    float v = 0.0f;
    if (n < 128)       v = Wq[n * 128 + k];
    else if (n < 256)  v = Wg[(n - 128) * 128 + k];
    else if (n < 512) {
      int c = n - 256, h = c >> 6, r = c & 63, ml = r >> 2, j = r & 3;
      int d = 2 * ml + (j & 1);
      v = (j < 2) ? Wk[(h * 32 + d) * 128 + k] : Wv[(h * 32 + d) * 128 + k];
    } else if (n < 516) v = Wb[(n - 512) * 128 + k];
    Wc[t] = f2bf(v);
  } else if (t < NPAD * INF + OUTF * 128) {
    int u = t - NPAD * INF;
    Woutb[u] = f2bf(Wout[u]);
  }
}

// ---------------------------------------------------------------------------
// Kernel 2: projection GEMM for the GATHERED quantities only:
//   kvb[E x 256] = Z @ Wc[256:512]^T,  bb[E x 4] = (Z @ Wc[512:516]^T)*log2e
// Latency-bound -> maximize TLP: 32 edges/block (6250 blocks), each wave
// owns ONE 4-tile kv group. Z loads duplicate across the 4 waves (L1/L2).
// ---------------------------------------------------------------------------
__global__ __launch_bounds__(256) void proj_kernel(
    const float* __restrict__ Z, const u16* __restrict__ Wc,
    u16* __restrict__ kvb, float* __restrict__ bb)
{
  __shared__ u16 stage[4][2048];   // [wave][32 rows x 64 cols]  (16 KB)

  const int wid = threadIdx.x >> 6, lane = threadIdx.x & 63;
  const int ml = lane & 15, blk = lane >> 4;
  const long e0 = (long)blockIdx.x * 32;

  bf16x8 zfr[2][4];
  load_zfr(Z, e0, ml, blk, zfr);

  // one 4-tile group per wave -> kvb col range [wid*64, wid*64+64)
  {
    u16* sb = stage[wid];
#pragma unroll
    for (int t = 0; t < 4; ++t) {
      AccPair acc = tile_mm(Wc, 256 + (wid * 4 + t) * 16, ml, blk, zfr, INF);
      uint2 pa, pb;
      pa.x = cvtpk_bf16(acc.a[0], acc.a[1]); pa.y = cvtpk_bf16(acc.a[2], acc.a[3]);
      pb.x = cvtpk_bf16(acc.b[0], acc.b[1]); pb.y = cvtpk_bf16(acc.b[2], acc.b[3]);
      ds_stage_pair(sb, ml, blk, t, pa, pb);
    }
    flush_group(sb, lane, kvb, e0, 256, wid * 64);
  }

  // --- b tile: Wc rows 512..515, prescaled by log2(e) for exp2 softmax ---
  if (wid == 3) {
    AccPair acc = tile_mm(Wc, 512, ml, blk, zfr, INF);
    if (blk == 0) {   // rows 512..515 only
      *(f32x4*)(bb + (e0 + ml) * 4) =
          (f32x4){acc.a[0] * LOG2E, acc.a[1] * LOG2E,
                  acc.a[2] * LOG2E, acc.a[3] * LOG2E};
      *(f32x4*)(bb + (e0 + 16 + ml) * 4) =
          (f32x4){acc.b[0] * LOG2E, acc.b[1] * LOG2E,
                  acc.b[2] * LOG2E, acc.b[3] * LOG2E};
    }
  }
}

// ---------------------------------------------------------------------------
// Kernel 3: fused q/g projection + gathered attention + output GEMM.
// Block = 4 waves = 32 edges. xs aliases qs (phase B overwrites q with x
// in-place, wave-exclusive rows). Gather loads one 8B [k-pair|v-pair] per
// lane per neighbor (interleaved kvb layout). Softmax in base-2.
// ---------------------------------------------------------------------------
__global__ __launch_bounds__(256) void attn_out_kernel(
    const float* __restrict__ Z, const u16* __restrict__ Wc,
    const float* __restrict__ bg,
    const int* __restrict__ klist, const u16* __restrict__ kvb,
    const float* __restrict__ bb, const u16* __restrict__ Woutb,
    const float* __restrict__ bout, float* __restrict__ out)
{
  __shared__ u16 qs[32 * XPAD];    // q in phase A/B, x in phase B/C (aliased)
  __shared__ u16 gs[32 * XPAD];

  const int wid = threadIdx.x >> 6;
  const int lane = threadIdx.x & 63;
  const long e0 = (long)blockIdx.x * 32;
  const int ml = lane & 15, blk = lane >> 4;

  // ---- Phase A: q/g projection for this block's 32 edges ----
  {
    bf16x8 zfr[2][4];
    load_zfr(Z, e0, ml, blk, zfr);

#pragma unroll
    for (int t = 0; t < 2; ++t) {
      const int nt = wid * 2 + t;             // q tile in [0,8)
      AccPair acc = tile_mm(Wc, nt * 16, ml, blk, zfr, INF);
      const int n0 = nt * 16 + blk * 4;
      uint2 pa, pb;
      pa.x = cvtpk_bf16(acc.a[0], acc.a[1]); pa.y = cvtpk_bf16(acc.a[2], acc.a[3]);
      pb.x = cvtpk_bf16(acc.b[0], acc.b[1]); pb.y = cvtpk_bf16(acc.b[2], acc.b[3]);
      *(uint2*)(&qs[ml * XPAD + n0]) = pa;
      *(uint2*)(&qs[(16 + ml) * XPAD + n0]) = pb;
    }
#pragma unroll
    for (int t = 0; t < 2; ++t) {
      const int nt = wid * 2 + t;             // g tile in [0,8)
      AccPair acc = tile_mm(Wc, 128 + nt * 16, ml, blk, zfr, INF);
      const int n0 = nt * 16 + blk * 4;
      float4 b4 = *(const float4*)(bg + n0);
      uint2 pa, pb;
      pa.x = cvtpk_bf16(sigm(acc.a[0] + b4.x), sigm(acc.a[1] + b4.y));
      pa.y = cvtpk_bf16(sigm(acc.a[2] + b4.z), sigm(acc.a[3] + b4.w));
      pb.x = cvtpk_bf16(sigm(acc.b[0] + b4.x), sigm(acc.b[1] + b4.y));
      pb.y = cvtpk_bf16(sigm(acc.b[2] + b4.z), sigm(acc.b[3] + b4.w));
      *(uint2*)(&gs[ml * XPAD + n0]) = pa;
      *(uint2*)(&gs[(16 + ml) * XPAD + n0]) = pb;
    }
  }
  __syncthreads();

  // ---- Phase B: gathered attention, one edge per wave-iteration ----
  const int h = lane >> 4;
  const int kvo = h * 64 + (lane & 15) * 4;   // u16 offset: [k0,k1,v0,v1]

#pragma unroll 1
  for (int it = 0; it < 8; ++it) {
    const int le = wid * 8 + it;
    int e = (int)e0 + le;
    e = __builtin_amdgcn_readfirstlane(e);   // wave-uniform -> SGPR

    const uint32_t q2 = *(const uint32_t*)(&qs[le * XPAD + 2 * lane]);
    const uint32_t g2 = *(const uint32_t*)(&gs[le * XPAD + 2 * lane]);
    const float q0 = bflo(q2), q1 = bfhi(q2);

    float sc[MAXK];
    uint32_t vvm[MAXK];
    const int* kl = klist + (size_t)e * 32;
#pragma unroll
    for (int nb = 0; nb < MAXK; ++nb) {
      const int ii = kl[nb];
      const int jj = kl[16 + nb];
      const bool valid = (ii >= 0);
      const int is = valid ? ii : 0;
      const int js = valid ? jj : 0;
      uint2 kv4 = *(const uint2*)(kvb + (size_t)is * 256 + kvo);  // 8B: k|v
      float p = q0 * bflo(kv4.x) + q1 * bfhi(kv4.x);
      p = row16_sum(p);                                 // head-wide dot
      float bj = bb[(size_t)js * 4 + h];                // prescaled by log2e
      sc[nb]  = valid ? fmaf(SCALE2, p, bj) : 0.0f;     // base-2 score
      vvm[nb] = valid ? kv4.y : 0u;
    }

    float m = sc[0];
#pragma unroll
    for (int nb = 1; nb < MAXK; ++nb) m = fmaxf(m, sc[nb]);
    float s = 0.f, a0 = 0.f, a1 = 0.f;
#pragma unroll
    for (int nb = 0; nb < MAXK; ++nb) {
      float al = exp2f(sc[nb] - m);                     // bare v_exp_f32
      s += al;
      a0 += al * bflo(vvm[nb]);
      a1 += al * bfhi(vvm[nb]);
    }
    float inv = 1.0f / s;
    uint32_t xo = cvtpk_bf16(bflo(g2) * a0 * inv, bfhi(g2) * a1 * inv);
    *(uint32_t*)(&qs[le * XPAD + 2 * lane]) = xo;   // x overwrites q (aliased)
  }

  __syncthreads();

  // ---- Phase C: output GEMM, 32 edges x 128 out, K = 128 ----
  bf16x8 xfr[2][4];
#pragma unroll
  for (int s = 0; s < 2; ++s) {
#pragma unroll
    for (int kk = 0; kk < 4; ++kk)
      xfr[s][kk] = *(const bf16x8*)(&qs[(s * 16 + ml) * XPAD + kk * 32 + blk * 8]);
  }

  const long eA = e0 + ml, eB = e0 + 16 + ml;

#pragma unroll
  for (int t = 0; t < 2; ++t) {
    const int nt = wid * 2 + t;
    AccPair acc = tile_mm(Woutb, nt * 16, ml, blk, xfr, 128);
    const int o0 = nt * 16 + blk * 4;
    float4 b4 = *(const float4*)(bout + o0);
    float4 ra = make_float4(acc.a[0] + b4.x, acc.a[1] + b4.y,
                            acc.a[2] + b4.z, acc.a[3] + b4.w);
    float4 rb = make_float4(acc.b[0] + b4.x, acc.b[1] + b4.y,
                            acc.b[2] + b4.z, acc.b[3] + b4.w);
    *(float4*)(out + eA * 128 + o0) = ra;
    *(float4*)(out + eB * 128 + o0) = rb;
  }
}

// ---------------------------------------------------------------------------
extern "C" void kernel_launch(void* const* d_in, const int* in_sizes, int n_in,
                              void* d_out, int out_size, void* d_ws, size_t ws_size,
                              hipStream_t stream) {
  const float* Z     = (const float*)d_in[0];
  const int*   klist = (const int*)  d_in[1];
  const float* Wq    = (const float*)d_in[2];
  const float* Wk    = (const float*)d_in[3];
  const float* Wv    = (const float*)d_in[4];
  const float* Wb    = (const float*)d_in[5];
  const float* Wg    = (const float*)d_in[6];
  const float* bg    = (const float*)d_in[7];
  const float* Wout  = (const float*)d_in[8];
  const float* bout  = (const float*)d_in[9];
  float* out = (float*)d_out;

  char* ws = (char*)d_ws;
  u16*   Wc    = (u16*)(ws);                        //   528*128*2   = 135168
  u16*   Woutb = (u16*)(ws + 135168);               //   128*128*2   =  32768
  u16*   kvb   = (u16*)(ws + 167936);               // E*256*2 = 102.4 MB
  float* bb    = (float*)(ws + 102567936);          // E*4*4   = 3.2 MB

  prep_kernel<<<(NPAD * INF + OUTF * 128 + 255) / 256, 256, 0, stream>>>(
      Wq, Wk, Wv, Wb, Wg, Wout, Wc, Woutb);
  proj_kernel<<<EDGES / 32, 256, 0, stream>>>(
      Z, Wc, kvb, bb);
  attn_out_kernel<<<EDGES / 32, 256, 0, stream>>>(
      Z, Wc, bg, klist, kvb, bb, Woutb, bout, out);
}

// Round 10
// 534.574 us; speedup vs baseline: 1.8569x; 1.8052x over previous
//
#include <hip/hip_runtime.h>
#include <hip/hip_bf16.h>
#include <stdint.h>

#define EDGES 200000
#define INF   128
#define HID   32
#define NHEAD 4
#define OUTF  128
#define MAXK  16

// combined-projection feature count: q(128) g(128) kv(256) b(4) pad(12)
#define NPAD  528

// LDS row stride in u16 for per-edge 128-col tiles (q/g/x)
#define XPAD  136

typedef unsigned short u16;
typedef __attribute__((ext_vector_type(8))) short bf16x8;   // 8 bf16 = 4 VGPRs
typedef __attribute__((ext_vector_type(4))) float f32x4;

__device__ __forceinline__ u16 f2bf(float f) {   // RNE f32->bf16
  union { float f; uint32_t u; } v; v.f = f;
  uint32_t u = v.u;
  return (u16)((u + 0x7FFFu + ((u >> 16) & 1u)) >> 16);
}
__device__ __forceinline__ float bflo(uint32_t p) {   // low bf16 of packed pair
  union { uint32_t u; float f; } v; v.u = p << 16;
  return v.f;
}
__device__ __forceinline__ float bfhi(uint32_t p) {   // high bf16 of packed pair
  union { uint32_t u; float f; } v; v.u = p & 0xFFFF0000u;
  return v.f;
}

// packed f32x2 -> bf16x2 (RNE), lets compiler emit v_cvt_pk_bf16_f32
__device__ __forceinline__ uint32_t cvtpk_bf16(float lo, float hi) {
  float2 t; t.x = lo; t.y = hi;
  __hip_bfloat162 h = __float22bfloat162_rn(t);
  uint32_t u;
  __builtin_memcpy(&u, &h, 4);
  return u;
}
__device__ __forceinline__ bf16x8 pack8(float4 f0, float4 f1) {
  union { uint32_t u[4]; bf16x8 v; } r;
  r.u[0] = cvtpk_bf16(f0.x, f0.y);
  r.u[1] = cvtpk_bf16(f0.z, f0.w);
  r.u[2] = cvtpk_bf16(f1.x, f1.y);
  r.u[3] = cvtpk_bf16(f1.z, f1.w);
  return r.v;
}
__device__ __forceinline__ float sigm(float x) {
  return 1.0f / (1.0f + __expf(-x));
}

// DPP-based add within each 16-lane row (one head). bound_ctrl=1, full masks.
template <int CTRL>
__device__ __forceinline__ float dpp_add(float x) {
  int y = __builtin_amdgcn_update_dpp(0, __builtin_bit_cast(int, x),
                                      CTRL, 0xF, 0xF, true);
  return x + __builtin_bit_cast(float, y);
}
__device__ __forceinline__ float row16_sum(float x) {
  x = dpp_add<0xB1>(x);
  x = dpp_add<0x4E>(x);
  x = dpp_add<0x141>(x);
  x = dpp_add<0x140>(x);
  return x;
}

// one 16(n) x 32(e) output tile: A = W rows (M=n), B = Z/x rows (N=e).
// D per lane: col(e) = lane&15, row(n) = (lane>>4)*4 + r  -> 4 consecutive n.
struct AccPair { f32x4 a, b; };
__device__ __forceinline__ AccPair tile_mm(const u16* __restrict__ W, int row0,
                                           int ml, int blk,
                                           const bf16x8 (&zfr)[2][4], int ldw) {
  bf16x8 wfr[4];
#pragma unroll
  for (int kk = 0; kk < 4; ++kk)
    wfr[kk] = *(const bf16x8*)(W + (size_t)(row0 + ml) * ldw + kk * 32 + blk * 8);
  AccPair r;
  r.a = (f32x4){0.f, 0.f, 0.f, 0.f};
  r.b = (f32x4){0.f, 0.f, 0.f, 0.f};
#pragma unroll
  for (int kk = 0; kk < 4; ++kk) {
    r.a = __builtin_amdgcn_mfma_f32_16x16x32_bf16(wfr[kk], zfr[0][kk], r.a, 0, 0, 0);
    r.b = __builtin_amdgcn_mfma_f32_16x16x32_bf16(wfr[kk], zfr[1][kk], r.b, 0, 0, 0);
  }
  return r;
}

// load + bf16-pack the B-operand fragments (32 edges x K=128) for one wave.
// Plain cached loads (nontemporal regressed 2.7x in R8: nt bypasses caches).
__device__ __forceinline__ void load_zfr(const float* __restrict__ Z, long e0,
                                         int ml, int blk, bf16x8 (&zfr)[2][4]) {
#pragma unroll
  for (int s = 0; s < 2; ++s) {
    const float* zp = Z + (e0 + s * 16 + ml) * INF + blk * 8;
#pragma unroll
    for (int kk = 0; kk < 4; ++kk) {
      float4 f0 = *(const float4*)(zp + kk * 32);
      float4 f1 = *(const float4*)(zp + kk * 32 + 4);
      zfr[s][kk] = pack8(f0, f1);
    }
  }
}

// ---- per-wave LDS staging so every HBM store covers full 128B lines ----
__device__ __forceinline__ void ds_stage_pair(u16* sb, int ml, int blk, int t,
                                              uint2 pa, uint2 pb) {
  const int col2 = (t * 16 + blk * 4) * 2;          // byte col within 128B row
  const int swz = (ml & 7) << 4;
  *(uint2*)((char*)sb + ((ml * 128 + col2) ^ swz)) = pa;           // eA row
  *(uint2*)((char*)sb + (((16 + ml) * 128 + col2) ^ swz)) = pb;    // eB row
}
__device__ __forceinline__ void flush_group(const u16* sb, int lane,
                                            u16* __restrict__ dst, long e0,
                                            int rowu16, int colu16) {
  const int rr = lane >> 3;            // 8 rows per store inst
  const int c8 = (lane & 7) * 8;       // u16 col within the 64-col group
#pragma unroll
  for (int i = 0; i < 4; ++i) {
    const int row = i * 8 + rr;
    bf16x8 v = *(const bf16x8*)((const char*)sb +
                                ((row * 128 + c8 * 2) ^ ((row & 7) << 4)));
    *(bf16x8*)(dst + (e0 + row) * rowu16 + colu16 + c8) = v;
  }
}

// ---------------------------------------------------------------------------
// Kernel 1: repack all projection weights into one bf16 matrix Wc[NPAD][128]
// rows: q 0..127, g 128..255, kv 256..511 INTERLEAVED, b 512..515.
// kv interleave: kvb col c: h = c>>6, r = c&63, ml = r>>2, j = r&3;
// j in {0,1} -> k dim 2ml+j, j in {2,3} -> v dim 2ml+(j-2).
// Each attn lane's k-pair and v-pair are ADJACENT -> one 8B gather.
// ---------------------------------------------------------------------------
__global__ __launch_bounds__(256) void prep_kernel(
    const float* __restrict__ Wq, const float* __restrict__ Wk,
    const float* __restrict__ Wv, const float* __restrict__ Wb,
    const float* __restrict__ Wg, const float* __restrict__ Wout,
    u16* __restrict__ Wc, u16* __restrict__ Woutb)
{
  int t = blockIdx.x * 256 + threadIdx.x;
  if (t < NPAD * INF) {
    int n = t >> 7, k = t & 127;
    float v = 0.0f;
    if (n < 128)       v = Wq[n * 128 + k];
    else if (n < 256)  v = Wg[(n - 128) * 128 + k];
    else if (n < 512) {
      int c = n - 256, h = c >> 6, r = c & 63, ml = r >> 2, j = r & 3;
      int d = 2 * ml + (j & 1);
      v = (j < 2) ? Wk[(h * 32 + d) * 128 + k] : Wv[(h * 32 + d) * 128 + k];
    } else if (n < 516) v = Wb[(n - 512) * 128 + k];
    Wc[t] = f2bf(v);
  } else if (t < NPAD * INF + OUTF * 128) {
    int u = t - NPAD * INF;
    Woutb[u] = f2bf(Wout[u]);
  }
}

// ---------------------------------------------------------------------------
// Kernel 2: projection GEMM for the GATHERED quantities only:
//   kvb[E x 256] = Z @ Wc[256:512]^T,  bb[E x 4] = Z @ Wc[512:516]^T
// Latency-bound -> maximize TLP: 32 edges/block (6250 blocks), each wave
// owns ONE 4-tile kv group. Z loads duplicate across the 4 waves (L1/L2).
// ---------------------------------------------------------------------------
__global__ __launch_bounds__(256) void proj_kernel(
    const float* __restrict__ Z, const u16* __restrict__ Wc,
    u16* __restrict__ kvb, float* __restrict__ bb)
{
  __shared__ u16 stage[4][2048];   // [wave][32 rows x 64 cols]  (16 KB)

  const int wid = threadIdx.x >> 6, lane = threadIdx.x & 63;
  const int ml = lane & 15, blk = lane >> 4;
  const long e0 = (long)blockIdx.x * 32;

  bf16x8 zfr[2][4];
  load_zfr(Z, e0, ml, blk, zfr);

  // one 4-tile group per wave -> kvb col range [wid*64, wid*64+64)
  {
    u16* sb = stage[wid];
#pragma unroll
    for (int t = 0; t < 4; ++t) {
      AccPair acc = tile_mm(Wc, 256 + (wid * 4 + t) * 16, ml, blk, zfr, INF);
      uint2 pa, pb;
      pa.x = cvtpk_bf16(acc.a[0], acc.a[1]); pa.y = cvtpk_bf16(acc.a[2], acc.a[3]);
      pb.x = cvtpk_bf16(acc.b[0], acc.b[1]); pb.y = cvtpk_bf16(acc.b[2], acc.b[3]);
      ds_stage_pair(sb, ml, blk, t, pa, pb);
    }
    flush_group(sb, lane, kvb, e0, 256, wid * 64);
  }

  // --- b tile: Wc rows 512..515 ---
  if (wid == 3) {
    AccPair acc = tile_mm(Wc, 512, ml, blk, zfr, INF);
    if (blk == 0) {   // rows 512..515 only
      *(f32x4*)(bb + (e0 + ml) * 4) =
          (f32x4){acc.a[0], acc.a[1], acc.a[2], acc.a[3]};
      *(f32x4*)(bb + (e0 + 16 + ml) * 4) =
          (f32x4){acc.b[0], acc.b[1], acc.b[2], acc.b[3]};
    }
  }
}

// ---------------------------------------------------------------------------
// Kernel 3: fused q/g projection + gathered attention + output GEMM.
// Block = 4 waves = 32 edges. xs aliases qs. Phase B: one edge per wave
// iteration; klist values are EXPLICITLY readfirstlane'd into SGPRs.
// (R9 diagnosis: the compiler silently lost klist scalarization — SGPR
// count 96->32 — so klist loads became vector loads sharing the in-order
// vmcnt queue with the kv gathers; each address wait then drained all
// outstanding gathers -> full serialization, 2.7x. Pinning the uniform
// values to SGPRs restores the s_load path regardless of optimizer mood.)
// ---------------------------------------------------------------------------
__global__ __launch_bounds__(256) void attn_out_kernel(
    const float* __restrict__ Z, const u16* __restrict__ Wc,
    const float* __restrict__ bg,
    const int* __restrict__ klist, const u16* __restrict__ kvb,
    const float* __restrict__ bb, const u16* __restrict__ Woutb,
    const float* __restrict__ bout, float* __restrict__ out)
{
  __shared__ u16 qs[32 * XPAD];    // q in phase A/B, x in phase B/C (aliased)
  __shared__ u16 gs[32 * XPAD];

  const int wid = threadIdx.x >> 6;
  const int lane = threadIdx.x & 63;
  const long e0 = (long)blockIdx.x * 32;
  const int ml = lane & 15, blk = lane >> 4;

  // ---- Phase A: q/g projection for this block's 32 edges ----
  {
    bf16x8 zfr[2][4];
    load_zfr(Z, e0, ml, blk, zfr);

#pragma unroll
    for (int t = 0; t < 2; ++t) {
      const int nt = wid * 2 + t;             // q tile in [0,8)
      AccPair acc = tile_mm(Wc, nt * 16, ml, blk, zfr, INF);
      const int n0 = nt * 16 + blk * 4;
      uint2 pa, pb;
      pa.x = cvtpk_bf16(acc.a[0], acc.a[1]); pa.y = cvtpk_bf16(acc.a[2], acc.a[3]);
      pb.x = cvtpk_bf16(acc.b[0], acc.b[1]); pb.y = cvtpk_bf16(acc.b[2], acc.b[3]);
      *(uint2*)(&qs[ml * XPAD + n0]) = pa;
      *(uint2*)(&qs[(16 + ml) * XPAD + n0]) = pb;
    }
#pragma unroll
    for (int t = 0; t < 2; ++t) {
      const int nt = wid * 2 + t;             // g tile in [0,8)
      AccPair acc = tile_mm(Wc, 128 + nt * 16, ml, blk, zfr, INF);
      const int n0 = nt * 16 + blk * 4;
      float4 b4 = *(const float4*)(bg + n0);
      uint2 pa, pb;
      pa.x = cvtpk_bf16(sigm(acc.a[0] + b4.x), sigm(acc.a[1] + b4.y));
      pa.y = cvtpk_bf16(sigm(acc.a[2] + b4.z), sigm(acc.a[3] + b4.w));
      pb.x = cvtpk_bf16(sigm(acc.b[0] + b4.x), sigm(acc.b[1] + b4.y));
      pb.y = cvtpk_bf16(sigm(acc.b[2] + b4.z), sigm(acc.b[3] + b4.w));
      *(uint2*)(&gs[ml * XPAD + n0]) = pa;
      *(uint2*)(&gs[(16 + ml) * XPAD + n0]) = pb;
    }
  }
  __syncthreads();

  // ---- Phase B: gathered attention, one edge per wave-iteration ----
  const int h = lane >> 4;
  const int kvo = h * 64 + (lane & 15) * 4;   // u16 offset: [k0,k1,v0,v1]
  const float scale = 0.17677669529663687f;   // 1/sqrt(32)

#pragma unroll 1
  for (int it = 0; it < 8; ++it) {
    const int le = wid * 8 + it;
    int e = (int)e0 + le;
    e = __builtin_amdgcn_readfirstlane(e);   // wave-uniform -> SGPR

    const uint32_t q2 = *(const uint32_t*)(&qs[le * XPAD + 2 * lane]);
    const uint32_t g2 = *(const uint32_t*)(&gs[le * XPAD + 2 * lane]);
    const float q0 = bflo(q2), q1 = bfhi(q2);

    float sc[MAXK];
    uint32_t vvm[MAXK];
    const int* kl = klist + (size_t)e * 32;
#pragma unroll
    for (int nb = 0; nb < MAXK; ++nb) {
      // values are wave-uniform; PIN them to SGPRs (see header comment)
      const int ii = __builtin_amdgcn_readfirstlane(kl[nb]);
      const int jj = __builtin_amdgcn_readfirstlane(kl[16 + nb]);
      const bool valid = (ii >= 0);
      const int is = valid ? ii : 0;
      const int js = valid ? jj : 0;
      uint2 kv4 = *(const uint2*)(kvb + (size_t)is * 256 + kvo);  // 8B: k|v
      float p = q0 * bflo(kv4.x) + q1 * bfhi(kv4.x);
      p = row16_sum(p);                                 // head-wide dot
      float bj = bb[(size_t)js * 4 + h];
      sc[nb]  = valid ? (scale * p + bj) : 0.0f;
      vvm[nb] = valid ? kv4.y : 0u;
    }

    float m = sc[0];
#pragma unroll
    for (int nb = 1; nb < MAXK; ++nb) m = fmaxf(m, sc[nb]);
    float s = 0.f, a0 = 0.f, a1 = 0.f;
#pragma unroll
    for (int nb = 0; nb < MAXK; ++nb) {
      float al = __expf(sc[nb] - m);
      s += al;
      a0 += al * bflo(vvm[nb]);
      a1 += al * bfhi(vvm[nb]);
    }
    float inv = 1.0f / s;
    uint32_t xo = cvtpk_bf16(bflo(g2) * a0 * inv, bfhi(g2) * a1 * inv);
    *(uint32_t*)(&qs[le * XPAD + 2 * lane]) = xo;   // x overwrites q (aliased)
  }

  __syncthreads();

  // ---- Phase C: output GEMM, 32 edges x 128 out, K = 128 ----
  bf16x8 xfr[2][4];
#pragma unroll
  for (int s = 0; s < 2; ++s) {
#pragma unroll
    for (int kk = 0; kk < 4; ++kk)
      xfr[s][kk] = *(const bf16x8*)(&qs[(s * 16 + ml) * XPAD + kk * 32 + blk * 8]);
  }

  const long eA = e0 + ml, eB = e0 + 16 + ml;

#pragma unroll
  for (int t = 0; t < 2; ++t) {
    const int nt = wid * 2 + t;
    AccPair acc = tile_mm(Woutb, nt * 16, ml, blk, xfr, 128);
    const int o0 = nt * 16 + blk * 4;
    float4 b4 = *(const float4*)(bout + o0);
    float4 ra = make_float4(acc.a[0] + b4.x, acc.a[1] + b4.y,
                            acc.a[2] + b4.z, acc.a[3] + b4.w);
    float4 rb = make_float4(acc.b[0] + b4.x, acc.b[1] + b4.y,
                            acc.b[2] + b4.z, acc.b[3] + b4.w);
    *(float4*)(out + eA * 128 + o0) = ra;
    *(float4*)(out + eB * 128 + o0) = rb;
  }
}

// ---------------------------------------------------------------------------
extern "C" void kernel_launch(void* const* d_in, const int* in_sizes, int n_in,
                              void* d_out, int out_size, void* d_ws, size_t ws_size,
                              hipStream_t stream) {
  const float* Z     = (const float*)d_in[0];
  const int*   klist = (const int*)  d_in[1];
  const float* Wq    = (const float*)d_in[2];
  const float* Wk    = (const float*)d_in[3];
  const float* Wv    = (const float*)d_in[4];
  const float* Wb    = (const float*)d_in[5];
  const float* Wg    = (const float*)d_in[6];
  const float* bg    = (const float*)d_in[7];
  const float* Wout  = (const float*)d_in[8];
  const float* bout  = (const float*)d_in[9];
  float* out = (float*)d_out;

  char* ws = (char*)d_ws;
  u16*   Wc    = (u16*)(ws);                        //   528*128*2   = 135168
  u16*   Woutb = (u16*)(ws + 135168);               //   128*128*2   =  32768
  u16*   kvb   = (u16*)(ws + 167936);               // E*256*2 = 102.4 MB
  float* bb    = (float*)(ws + 102567936);          // E*4*4   = 3.2 MB

  prep_kernel<<<(NPAD * INF + OUTF * 128 + 255) / 256, 256, 0, stream>>>(
      Wq, Wk, Wv, Wb, Wg, Wout, Wc, Woutb);
  proj_kernel<<<EDGES / 32, 256, 0, stream>>>(
      Z, Wc, kvb, bb);
  attn_out_kernel<<<EDGES / 32, 256, 0, stream>>>(
      Z, Wc, bg, klist, kvb, bb, Woutb, bout, out);
}

// Round 12
// 517.927 us; speedup vs baseline: 1.9166x; 1.0321x over previous
//
#include <hip/hip_runtime.h>
#include <hip/hip_bf16.h>
#include <stdint.h>

#define EDGES 200000
#define INF   128
#define HID   32
#define NHEAD 4
#define OUTF  128
#define MAXK  16

// combined-projection feature count: q(128) g(128) kv(256) b(4) pad(12)
#define NPAD  528

// LDS row stride in u16 for per-edge 128-col tiles (q/g/x)
#define XPAD  136

typedef unsigned short u16;
typedef __attribute__((ext_vector_type(8))) short bf16x8;   // 8 bf16 = 4 VGPRs
typedef __attribute__((ext_vector_type(4))) float f32x4;
typedef __attribute__((ext_vector_type(16))) int i32x16;

__device__ __forceinline__ u16 f2bf(float f) {   // RNE f32->bf16
  union { float f; uint32_t u; } v; v.f = f;
  uint32_t u = v.u;
  return (u16)((u + 0x7FFFu + ((u >> 16) & 1u)) >> 16);
}
__device__ __forceinline__ float bflo(uint32_t p) {   // low bf16 of packed pair
  union { uint32_t u; float f; } v; v.u = p << 16;
  return v.f;
}
__device__ __forceinline__ float bfhi(uint32_t p) {   // high bf16 of packed pair
  union { uint32_t u; float f; } v; v.u = p & 0xFFFF0000u;
  return v.f;
}

// packed f32x2 -> bf16x2 (RNE), lets compiler emit v_cvt_pk_bf16_f32
__device__ __forceinline__ uint32_t cvtpk_bf16(float lo, float hi) {
  float2 t; t.x = lo; t.y = hi;
  __hip_bfloat162 h = __float22bfloat162_rn(t);
  uint32_t u;
  __builtin_memcpy(&u, &h, 4);
  return u;
}
__device__ __forceinline__ bf16x8 pack8(float4 f0, float4 f1) {
  union { uint32_t u[4]; bf16x8 v; } r;
  r.u[0] = cvtpk_bf16(f0.x, f0.y);
  r.u[1] = cvtpk_bf16(f0.z, f0.w);
  r.u[2] = cvtpk_bf16(f1.x, f1.y);
  r.u[3] = cvtpk_bf16(f1.z, f1.w);
  return r.v;
}
__device__ __forceinline__ float sigm(float x) {
  return 1.0f / (1.0f + __expf(-x));
}

// DPP-based add within each 16-lane row (one head). bound_ctrl=1, full masks.
template <int CTRL>
__device__ __forceinline__ float dpp_add(float x) {
  int y = __builtin_amdgcn_update_dpp(0, __builtin_bit_cast(int, x),
                                      CTRL, 0xF, 0xF, true);
  return x + __builtin_bit_cast(float, y);
}
__device__ __forceinline__ float row16_sum(float x) {
  x = dpp_add<0xB1>(x);
  x = dpp_add<0x4E>(x);
  x = dpp_add<0x141>(x);
  x = dpp_add<0x140>(x);
  return x;
}

// one 16(n) x 32(e) output tile: A = W rows (M=n), B = Z/x rows (N=e).
// D per lane: col(e) = lane&15, row(n) = (lane>>4)*4 + r  -> 4 consecutive n.
struct AccPair { f32x4 a, b; };
__device__ __forceinline__ AccPair tile_mm(const u16* __restrict__ W, int row0,
                                           int ml, int blk,
                                           const bf16x8 (&zfr)[2][4], int ldw) {
  bf16x8 wfr[4];
#pragma unroll
  for (int kk = 0; kk < 4; ++kk)
    wfr[kk] = *(const bf16x8*)(W + (size_t)(row0 + ml) * ldw + kk * 32 + blk * 8);
  AccPair r;
  r.a = (f32x4){0.f, 0.f, 0.f, 0.f};
  r.b = (f32x4){0.f, 0.f, 0.f, 0.f};
#pragma unroll
  for (int kk = 0; kk < 4; ++kk) {
    r.a = __builtin_amdgcn_mfma_f32_16x16x32_bf16(wfr[kk], zfr[0][kk], r.a, 0, 0, 0);
    r.b = __builtin_amdgcn_mfma_f32_16x16x32_bf16(wfr[kk], zfr[1][kk], r.b, 0, 0, 0);
  }
  return r;
}

// load + bf16-pack the B-operand fragments (32 edges x K=128) for one wave.
__device__ __forceinline__ void load_zfr(const float* __restrict__ Z, long e0,
                                         int ml, int blk, bf16x8 (&zfr)[2][4]) {
#pragma unroll
  for (int s = 0; s < 2; ++s) {
    const float* zp = Z + (e0 + s * 16 + ml) * INF + blk * 8;
#pragma unroll
    for (int kk = 0; kk < 4; ++kk) {
      float4 f0 = *(const float4*)(zp + kk * 32);
      float4 f1 = *(const float4*)(zp + kk * 32 + 4);
      zfr[s][kk] = pack8(f0, f1);
    }
  }
}

// ---- per-wave LDS staging so every HBM store covers full 128B lines ----
__device__ __forceinline__ void ds_stage_pair(u16* sb, int ml, int blk, int t,
                                              uint2 pa, uint2 pb) {
  const int col2 = (t * 16 + blk * 4) * 2;          // byte col within 128B row
  const int swz = (ml & 7) << 4;
  *(uint2*)((char*)sb + ((ml * 128 + col2) ^ swz)) = pa;           // eA row
  *(uint2*)((char*)sb + (((16 + ml) * 128 + col2) ^ swz)) = pb;    // eB row
}
__device__ __forceinline__ void flush_group(const u16* sb, int lane,
                                            u16* __restrict__ dst, long e0,
                                            int rowu16, int colu16) {
  const int rr = lane >> 3;            // 8 rows per store inst
  const int c8 = (lane & 7) * 8;       // u16 col within the 64-col group
#pragma unroll
  for (int i = 0; i < 4; ++i) {
    const int row = i * 8 + rr;
    bf16x8 v = *(const bf16x8*)((const char*)sb +
                                ((row * 128 + c8 * 2) ^ ((row & 7) << 4)));
    *(bf16x8*)(dst + (e0 + row) * rowu16 + colu16 + c8) = v;
  }
}

// ---------------------------------------------------------------------------
// Kernel 1: repack all projection weights into one bf16 matrix Wc[NPAD][128]
// rows: q 0..127, g 128..255, kv 256..511 INTERLEAVED, b 512..515.
// kv interleave: kvb col c: h = c>>6, r = c&63, m = r>>2, j = r&3;
// j in {0,1} -> k dim 2m+j, j in {2,3} -> v dim 2m+(j-2).
// Each attn lane's k-pair and v-pair are ADJACENT -> one 8B gather.
// ---------------------------------------------------------------------------
__global__ __launch_bounds__(256) void prep_kernel(
    const float* __restrict__ Wq, const float* __restrict__ Wk,
    const float* __restrict__ Wv, const float* __restrict__ Wb,
    const float* __restrict__ Wg, const float* __restrict__ Wout,
    u16* __restrict__ Wc, u16* __restrict__ Woutb)
{
  int t = blockIdx.x * 256 + threadIdx.x;
  if (t < NPAD * INF) {
    int n = t >> 7, k = t & 127;
    float v = 0.0f;
    if (n < 128)       v = Wq[n * 128 + k];
    else if (n < 256)  v = Wg[(n - 128) * 128 + k];
    else if (n < 512) {
      int c = n - 256, h = c >> 6, r = c & 63, m = r >> 2, j = r & 3;
      int d = 2 * m + (j & 1);
      v = (j < 2) ? Wk[(h * 32 + d) * 128 + k] : Wv[(h * 32 + d) * 128 + k];
    } else if (n < 516) v = Wb[(n - 512) * 128 + k];
    Wc[t] = f2bf(v);
  } else if (t < NPAD * INF + OUTF * 128) {
    int u = t - NPAD * INF;
    Woutb[u] = f2bf(Wout[u]);
  }
}

// ---------------------------------------------------------------------------
// Kernel 2: projection GEMM for the GATHERED quantities only:
//   kvb[E x 256] = Z @ Wc[256:512]^T,  bb[E x 4] = Z @ Wc[512:516]^T
// EXACT R6 shape (directly measured 100us): 128 edges/block (1563 blocks),
// each wave owns 32 edges, loads zfr ONCE, runs the full 16-kv-tile chain
// in four staged 4-tile groups + the b tile. (The R7 "more TLP" split to
// 32-edge blocks quadrupled Z-load instructions per tile computed and
// REGRESSED ~2x — the chain is load-latency-headed, amortization wins.)
// ---------------------------------------------------------------------------
__global__ __launch_bounds__(256) void proj_kernel(
    const float* __restrict__ Z, const u16* __restrict__ Wc,
    u16* __restrict__ kvb, float* __restrict__ bb)
{
  __shared__ u16 stage[4][2048];   // [wave][32 rows x 64 cols]  (16 KB)

  const int wid = threadIdx.x >> 6, lane = threadIdx.x & 63;
  const int ml = lane & 15, blk = lane >> 4;
  const long e0 = (long)blockIdx.x * 128 + wid * 32;
  if (e0 >= EDGES) return;   // EDGES % 32 == 0: waves are all-valid or all-out

  bf16x8 zfr[2][4];
  load_zfr(Z, e0, ml, blk, zfr);

  // --- kv: Wc rows 256..511 in four 4-tile groups -> kvb cols [0,256) ---
  for (int g = 0; g < 4; ++g) {
    u16* sb = stage[wid];
#pragma unroll
    for (int t = 0; t < 4; ++t) {
      AccPair acc = tile_mm(Wc, 256 + (g * 4 + t) * 16, ml, blk, zfr, INF);
      uint2 pa, pb;
      pa.x = cvtpk_bf16(acc.a[0], acc.a[1]); pa.y = cvtpk_bf16(acc.a[2], acc.a[3]);
      pb.x = cvtpk_bf16(acc.b[0], acc.b[1]); pb.y = cvtpk_bf16(acc.b[2], acc.b[3]);
      ds_stage_pair(sb, ml, blk, t, pa, pb);
    }
    flush_group(sb, lane, kvb, e0, 256, g * 64);
  }

  // --- b tile: Wc rows 512..515 ---
  {
    AccPair acc = tile_mm(Wc, 512, ml, blk, zfr, INF);
    if (blk == 0) {   // rows 512..515 only
      *(f32x4*)(bb + (e0 + ml) * 4) =
          (f32x4){acc.a[0], acc.a[1], acc.a[2], acc.a[3]};
      *(f32x4*)(bb + (e0 + 16 + ml) * 4) =
          (f32x4){acc.b[0], acc.b[1], acc.b[2], acc.b[3]};
    }
  }
}

// ---------------------------------------------------------------------------
// Kernel 3: fused q/g projection + gathered attention + output GEMM.
// Block = 4 waves = 32 edges. xs aliases qs. Phase B: one edge per wave
// iteration; the edge's klist row (16 ii + 16 jj) is fetched with TWO
// s_load_dwordx16 into SGPRs (scalar cache path, off the vmcnt queue) —
// structurally immune to the R9 scalarization loss (v-load klist shared
// the in-order vmcnt queue with gathers -> 2.7x serialization).
// ---------------------------------------------------------------------------
__global__ __launch_bounds__(256) void attn_out_kernel(
    const float* __restrict__ Z, const u16* __restrict__ Wc,
    const float* __restrict__ bg,
    const int* __restrict__ klist, const u16* __restrict__ kvb,
    const float* __restrict__ bb, const u16* __restrict__ Woutb,
    const float* __restrict__ bout, float* __restrict__ out)
{
  __shared__ u16 qs[32 * XPAD];    // q in phase A/B, x in phase B/C (aliased)
  __shared__ u16 gs[32 * XPAD];

  const int wid = threadIdx.x >> 6;
  const int lane = threadIdx.x & 63;
  const long e0 = (long)blockIdx.x * 32;
  const int ml = lane & 15, blk = lane >> 4;

  // ---- Phase A: q/g projection for this block's 32 edges ----
  {
    bf16x8 zfr[2][4];
    load_zfr(Z, e0, ml, blk, zfr);

#pragma unroll
    for (int t = 0; t < 2; ++t) {
      const int nt = wid * 2 + t;             // q tile in [0,8)
      AccPair acc = tile_mm(Wc, nt * 16, ml, blk, zfr, INF);
      const int n0 = nt * 16 + blk * 4;
      uint2 pa, pb;
      pa.x = cvtpk_bf16(acc.a[0], acc.a[1]); pa.y = cvtpk_bf16(acc.a[2], acc.a[3]);
      pb.x = cvtpk_bf16(acc.b[0], acc.b[1]); pb.y = cvtpk_bf16(acc.b[2], acc.b[3]);
      *(uint2*)(&qs[ml * XPAD + n0]) = pa;
      *(uint2*)(&qs[(16 + ml) * XPAD + n0]) = pb;
    }
#pragma unroll
    for (int t = 0; t < 2; ++t) {
      const int nt = wid * 2 + t;             // g tile in [0,8)
      AccPair acc = tile_mm(Wc, 128 + nt * 16, ml, blk, zfr, INF);
      const int n0 = nt * 16 + blk * 4;
      float4 b4 = *(const float4*)(bg + n0);
      uint2 pa, pb;
      pa.x = cvtpk_bf16(sigm(acc.a[0] + b4.x), sigm(acc.a[1] + b4.y));
      pa.y = cvtpk_bf16(sigm(acc.a[2] + b4.z), sigm(acc.a[3] + b4.w));
      pb.x = cvtpk_bf16(sigm(acc.b[0] + b4.x), sigm(acc.b[1] + b4.y));
      pb.y = cvtpk_bf16(sigm(acc.b[2] + b4.z), sigm(acc.b[3] + b4.w));
      *(uint2*)(&gs[ml * XPAD + n0]) = pa;
      *(uint2*)(&gs[(16 + ml) * XPAD + n0]) = pb;
    }
  }
  __syncthreads();

  // ---- Phase B: gathered attention, one edge per wave-iteration ----
  const int h = lane >> 4;
  const int kvo = h * 64 + (lane & 15) * 4;   // u16 offset: [k0,k1,v0,v1]
  const float scale = 0.17677669529663687f;   // 1/sqrt(32)

#pragma unroll 1
  for (int it = 0; it < 8; ++it) {
    const int le = wid * 8 + it;
    int e = (int)e0 + le;
    e = __builtin_amdgcn_readfirstlane(e);   // wave-uniform -> SGPR

    const uint32_t q2 = *(const uint32_t*)(&qs[le * XPAD + 2 * lane]);
    const uint32_t g2 = *(const uint32_t*)(&gs[le * XPAD + 2 * lane]);
    const float q0 = bflo(q2), q1 = bfhi(q2);

    // scalar-path fetch of this edge's whole klist row: 16 ii + 16 jj
    const int* kl = klist + (size_t)e * 32;
    i32x16 iiv, jjv;
    asm volatile("s_load_dwordx16 %0, %2, 0x0\n\t"
                 "s_load_dwordx16 %1, %2, 0x40\n\t"
                 "s_waitcnt lgkmcnt(0)"
                 : "=&s"(iiv), "=&s"(jjv)
                 : "s"(kl));

    float sc[MAXK];
    uint32_t vvm[MAXK];
#pragma unroll
    for (int nb = 0; nb < MAXK; ++nb) {
      const int ii = iiv[nb];
      const int jj = jjv[nb];
      const bool valid = (ii >= 0);
      const int is = valid ? ii : 0;
      const int js = valid ? jj : 0;
      uint2 kv4 = *(const uint2*)(kvb + (size_t)is * 256 + kvo);  // 8B: k|v
      float p = q0 * bflo(kv4.x) + q1 * bfhi(kv4.x);
      p = row16_sum(p);                                 // head-wide dot
      float bj = bb[(size_t)js * 4 + h];
      sc[nb]  = valid ? (scale * p + bj) : 0.0f;
      vvm[nb] = valid ? kv4.y : 0u;
    }

    float m = sc[0];
#pragma unroll
    for (int nb = 1; nb < MAXK; ++nb) m = fmaxf(m, sc[nb]);
    float s = 0.f, a0 = 0.f, a1 = 0.f;
#pragma unroll
    for (int nb = 0; nb < MAXK; ++nb) {
      float al = __expf(sc[nb] - m);
      s += al;
      a0 += al * bflo(vvm[nb]);
      a1 += al * bfhi(vvm[nb]);
    }
    float inv = 1.0f / s;
    uint32_t xo = cvtpk_bf16(bflo(g2) * a0 * inv, bfhi(g2) * a1 * inv);
    *(uint32_t*)(&qs[le * XPAD + 2 * lane]) = xo;   // x overwrites q (aliased)
  }

  __syncthreads();

  // ---- Phase C: output GEMM, 32 edges x 128 out, K = 128 ----
  bf16x8 xfr[2][4];
#pragma unroll
  for (int s = 0; s < 2; ++s) {
#pragma unroll
    for (int kk = 0; kk < 4; ++kk)
      xfr[s][kk] = *(const bf16x8*)(&qs[(s * 16 + ml) * XPAD + kk * 32 + blk * 8]);
  }

  const long eA = e0 + ml, eB = e0 + 16 + ml;

#pragma unroll
  for (int t = 0; t < 2; ++t) {
    const int nt = wid * 2 + t;
    AccPair acc = tile_mm(Woutb, nt * 16, ml, blk, xfr, 128);
    const int o0 = nt * 16 + blk * 4;
    float4 b4 = *(const float4*)(bout + o0);
    float4 ra = make_float4(acc.a[0] + b4.x, acc.a[1] + b4.y,
                            acc.a[2] + b4.z, acc.a[3] + b4.w);
    float4 rb = make_float4(acc.b[0] + b4.x, acc.b[1] + b4.y,
                            acc.b[2] + b4.z, acc.b[3] + b4.w);
    *(float4*)(out + eA * 128 + o0) = ra;
    *(float4*)(out + eB * 128 + o0) = rb;
  }
}

// ---------------------------------------------------------------------------
extern "C" void kernel_launch(void* const* d_in, const int* in_sizes, int n_in,
                              void* d_out, int out_size, void* d_ws, size_t ws_size,
                              hipStream_t stream) {
  const float* Z     = (const float*)d_in[0];
  const int*   klist = (const int*)  d_in[1];
  const float* Wq    = (const float*)d_in[2];
  const float* Wk    = (const float*)d_in[3];
  const float* Wv    = (const float*)d_in[4];
  const float* Wb    = (const float*)d_in[5];
  const float* Wg    = (const float*)d_in[6];
  const float* bg    = (const float*)d_in[7];
  const float* Wout  = (const float*)d_in[8];
  const float* bout  = (const float*)d_in[9];
  float* out = (float*)d_out;

  char* ws = (char*)d_ws;
  u16*   Wc    = (u16*)(ws);                        //   528*128*2   = 135168
  u16*   Woutb = (u16*)(ws + 135168);               //   128*128*2   =  32768
  u16*   kvb   = (u16*)(ws + 167936);               // E*256*2 = 102.4 MB
  float* bb    = (float*)(ws + 102567936);          // E*4*4   = 3.2 MB

  prep_kernel<<<(NPAD * INF + OUTF * 128 + 255) / 256, 256, 0, stream>>>(
      Wq, Wk, Wv, Wb, Wg, Wout, Wc, Woutb);
  proj_kernel<<<(EDGES + 127) / 128, 256, 0, stream>>>(
      Z, Wc, kvb, bb);
  attn_out_kernel<<<EDGES / 32, 256, 0, stream>>>(
      Z, Wc, bg, klist, kvb, bb, Woutb, bout, out);
}